// Round 7
// baseline (2363.240 us; speedup 1.0000x reference)
//
#include <hip/hip_runtime.h>
#include <stdint.h>

#define T_ 512
#define B_ 256
#define H_ 256

typedef __attribute__((ext_vector_type(4))) float f32x4;
typedef __attribute__((ext_vector_type(8))) short short8;
typedef unsigned short ushort_t;
typedef unsigned int uint_t;

__device__ __forceinline__ ushort_t f2bf(float f) {
  uint_t x = __float_as_uint(f);
  x += 0x7fffu + ((x >> 16) & 1u);
  return (ushort_t)(x >> 16);
}
__device__ __forceinline__ float bf2f(ushort_t u) {
  return __uint_as_float(((uint_t)u) << 16);
}
__device__ __forceinline__ float sigmoidf_(float x) {
  return 1.0f / (1.0f + __expf(-x));
}
__device__ __forceinline__ float tanhf_(float x) {
  return 1.0f - 2.0f / (__expf(2.0f * x) + 1.0f);
}

// ============ weight prep: fragment-linear bf16 tiles =======================
// Tile = 16 N-rows x 32 K, 512 elems, MFMA-B lane order:
//   elem[l*8+j] = W[n0 + (l&15)][k0 + (l>>4)*8 + j]
// Blob layout (ushort elems):
//   0       BRZ1 N=512 K=512 Kt=16 | 262144 BIN1 | 327680 BHN1   (layer1)
//   393216  BRZ0                   | 655360 BIN0 | 720896 BHN0   (layer0)
//   786432  BSH N=256 K=64 Kt=2    | 802816 BV1 N=256 K=256 Kt=8
__global__ __launch_bounds__(256) void k_prep(
    const float* __restrict__ w_ih, const float* __restrict__ w_hh,
    const float* __restrict__ w_shared, const float* __restrict__ w_v1,
    ushort_t* __restrict__ wdst) {
  int idx = blockIdx.x * 256 + threadIdx.x;
  if (idx >= 868352) return;
  float v;
  if (idx < 786432) {
    int half = (idx < 393216) ? 1 : 0;
    int d = (idx < 393216) ? idx : idx - 393216;
    const float* wi = w_ih + (half ? 196608 : 0);
    const float* wh = w_hh + (half ? 196608 : 0);
    if (d < 262144) {
      int t = d >> 9, q = d & 511, l = q >> 3, j = q & 7;
      int n = (t >> 4) * 16 + (l & 15);
      int k = (t & 15) * 32 + (l >> 4) * 8 + j;
      v = (k < 256) ? wi[n * 256 + k] : wh[n * 256 + (k - 256)];
    } else if (d < 327680) {
      int dd = d - 262144;
      int t = dd >> 9, q = dd & 511, l = q >> 3, j = q & 7;
      int n = (t >> 3) * 16 + (l & 15);
      int k = (t & 7) * 32 + (l >> 4) * 8 + j;
      v = wi[(512 + n) * 256 + k];
    } else {
      int dd = d - 327680;
      int t = dd >> 9, q = dd & 511, l = q >> 3, j = q & 7;
      int n = (t >> 3) * 16 + (l & 15);
      int k = (t & 7) * 32 + (l >> 4) * 8 + j;
      v = wh[(512 + n) * 256 + k];
    }
  } else if (idx < 802816) {
    int dd = idx - 786432;
    int t = dd >> 9, q = dd & 511, l = q >> 3, j = q & 7;
    int n = (t >> 1) * 16 + (l & 15);
    int k = (t & 1) * 32 + (l >> 4) * 8 + j;
    v = w_shared[n * 64 + k];
  } else {
    int dd = idx - 802816;
    int t = dd >> 9, q = dd & 511, l = q >> 3, j = q & 7;
    int n = (t >> 3) * 16 + (l & 15);
    int k = (t & 7) * 32 + (l >> 4) * 8 + j;
    v = w_v1[n * 256 + k];
  }
  wdst[idx] = f2bf(v);
}

// ============ parallel segment build ========================================
__global__ __launch_bounds__(256) void k_hist(
    const int* __restrict__ dones, int* __restrict__ gcur) {
  __shared__ int lh[513];
  int tid = threadIdx.x;
  for (int i = tid; i < 513; i += 256) lh[i] = 0;
  __syncthreads();
  int t = blockIdx.x, b = tid;
  bool start = (t == 0) || (dones[t * B_ + b] != 0);
  if (start) {
    int tt = t + 1;
    while (tt < T_ && dones[tt * B_ + b] == 0) ++tt;
    atomicAdd(&lh[tt - t], 1);
  }
  __syncthreads();
  for (int i = tid; i < 513; i += 256)
    if (lh[i]) atomicAdd(&gcur[i], lh[i]);
}

__global__ void k_scan(int* __restrict__ gcur, int* __restrict__ suf) {
  if (threadIdx.x != 0 || blockIdx.x != 0) return;
  int run = 0;
  suf[513] = 0;
  for (int k = 512; k >= 1; --k) {
    int h = gcur[k];
    gcur[k] = run;
    run += h;
    suf[k] = run;
  }
  suf[0] = run;
}

__global__ __launch_bounds__(256) void k_place(
    const int* __restrict__ dones, int* __restrict__ gcur,
    uint_t* __restrict__ segs) {
  __shared__ int lh[513];
  __shared__ int lbase[513];
  int tid = threadIdx.x;
  for (int i = tid; i < 513; i += 256) lh[i] = 0;
  __syncthreads();
  int t = blockIdx.x, b = tid;
  bool start = (t == 0) || (dones[t * B_ + b] != 0);
  int len = 0, lrank = 0;
  if (start) {
    int tt = t + 1;
    while (tt < T_ && dones[tt * B_ + b] == 0) ++tt;
    len = tt - t;
    lrank = atomicAdd(&lh[len], 1);
  }
  __syncthreads();
  for (int i = tid; i < 513; i += 256)
    if (lh[i]) lbase[i] = atomicAdd(&gcur[i], lh[i]);
  __syncthreads();
  if (start)
    segs[lbase[len] + lrank] = ((uint_t)b << 20) | ((uint_t)t << 10) | (uint_t)len;
}

// ============ fully fused persistent RNN ====================================
// Block owns 64 segments (one sorted chunk); loops positions internally.
// Per position: x->feats GEMM, GRU layer0, GRU layer1, value head — all from
// LDS, all intra-block. 1024 threads = 16 waves, wave w = 16-col slice.
__device__ __forceinline__ int aswz256(int m, int k) {
  return m * 256 + ((((k >> 3) ^ (m & 7)) << 3) | (k & 7));
}
__device__ __forceinline__ int aswz64(int m, int k) {
  return m * 64 + ((((k >> 3) ^ (m & 7)) << 3) | (k & 7));
}

#define MFMA_BF16 __builtin_amdgcn_mfma_f32_16x16x32_bf16

// One GRU layer: A = [Alo | hT], updates hT in place (own cols).
// Caller must place barriers: before (inputs ready) / between K and epi /
// after epi. This function does K-loop + returns acc; epi separate.
__device__ __forceinline__ void gru_kloop(
    const ushort_t* __restrict__ Alo, const ushort_t* __restrict__ hT,
    const ushort_t* __restrict__ Wl, int rt, int lrow, int lq, int l,
    f32x4 (&accR)[4], f32x4 (&accZ)[4], f32x4 (&accI)[4], f32x4 (&accH)[4]) {
  const ushort_t* Win = Wl + 262144;
  const ushort_t* Whn = Wl + 327680;
#pragma unroll
  for (int ks = 0; ks < 16; ++ks) {
    const ushort_t* atile = (ks < 8) ? Alo : hT;
    int kk = (ks & 7) * 32 + lq * 8;
    short8 a[4];
#pragma unroll
    for (int mt = 0; mt < 4; ++mt)
      a[mt] = *(const short8*)&atile[aswz256(mt * 16 + lrow, kk)];
    short8 bR = *(const short8*)&Wl[(size_t)((rt * 16 + ks) << 9) + l * 8];
    short8 bZ = *(const short8*)&Wl[(size_t)(((16 + rt) * 16 + ks) << 9) + l * 8];
#pragma unroll
    for (int mt = 0; mt < 4; ++mt) accR[mt] = MFMA_BF16(a[mt], bR, accR[mt], 0, 0, 0);
#pragma unroll
    for (int mt = 0; mt < 4; ++mt) accZ[mt] = MFMA_BF16(a[mt], bZ, accZ[mt], 0, 0, 0);
    if (ks < 8) {
      short8 bI = *(const short8*)&Win[(size_t)((rt * 8 + ks) << 9) + l * 8];
#pragma unroll
      for (int mt = 0; mt < 4; ++mt) accI[mt] = MFMA_BF16(a[mt], bI, accI[mt], 0, 0, 0);
    } else {
      short8 bH = *(const short8*)&Whn[(size_t)((rt * 8 + (ks - 8)) << 9) + l * 8];
#pragma unroll
      for (int mt = 0; mt < 4; ++mt) accH[mt] = MFMA_BF16(a[mt], bH, accH[mt], 0, 0, 0);
    }
  }
}

__device__ __forceinline__ void gru_epi(
    ushort_t* hT, int c, int lq,
    float br, float bz, float bi, float bh,
    f32x4 (&accR)[4], f32x4 (&accZ)[4], f32x4 (&accI)[4], f32x4 (&accH)[4]) {
#pragma unroll
  for (int mt = 0; mt < 4; ++mt) {
#pragma unroll
    for (int rg = 0; rg < 4; ++rg) {
      int m = mt * 16 + lq * 4 + rg;
      float hp = bf2f(hT[aswz256(m, c)]);
      float rr = sigmoidf_(accR[mt][rg] + br);
      float zz = sigmoidf_(accZ[mt][rg] + bz);
      float nn = tanhf_(accI[mt][rg] + bi + rr * (accH[mt][rg] + bh));
      float h = (1.f - zz) * nn + zz * hp;
      hT[aswz256(m, c)] = f2bf(h);
    }
  }
}

__global__ __launch_bounds__(1024, 1) void k_rnn(
    const float* __restrict__ x, const ushort_t* __restrict__ Wb,
    const uint_t* __restrict__ segs, const int* __restrict__ suf,
    const float* __restrict__ b_shared,
    const float* __restrict__ b_ih, const float* __restrict__ b_hh,
    const float* __restrict__ b_v1, const float* __restrict__ w_v2,
    const float* __restrict__ b_v2, float* __restrict__ out) {
  extern __shared__ __align__(16) ushort_t dyn[];
  ushort_t* fT  = dyn;                       // 64x256 = 16384
  ushort_t* h0T = dyn + 16384;               // 16384
  ushort_t* h1T = dyn + 32768;               // 16384
  ushort_t* xT  = dyn + 49152;               // 64x64 = 4096
  float* vred   = (float*)(dyn + 53248);     // 64*17 floats
  int* sB   = (int*)(dyn + 55424);           // 64
  int* sT0  = (int*)(dyn + 55552);
  int* sLen = (int*)(dyn + 55680);           // end 55808 ush = 111616 B

  int tid = threadIdx.x;
  int bid = blockIdx.x;
  int nseg = suf[1];

  // meta staging + h zero-init
  if (tid < 64) {
    int j = bid * 64 + tid;
    int jc = (j < nseg) ? j : (nseg - 1);
    uint_t sg = segs[jc];
    sB[tid] = (int)(sg >> 20);
    sT0[tid] = (int)((sg >> 10) & 1023);
    sLen[tid] = (j < nseg) ? (int)(sg & 1023) : 0;
  }
  {
    short8 z8 = {0, 0, 0, 0, 0, 0, 0, 0};
#pragma unroll
    for (int q = 0; q < 4; ++q) {
      int o = (tid + q * 1024) * 8;          // 32768 ushorts over h0T+h1T
      *(short8*)&h0T[o & 16383] = z8;        // q<2 -> h0T, q>=2 -> h1T
      if (q >= 2) *(short8*)&h1T[o & 16383] = z8;
      else *(short8*)&h0T[o & 16383] = z8;
    }
    // simpler correct re-do: zero both fully
#pragma unroll
    for (int q = 0; q < 2; ++q) {
      int o = (tid + q * 1024) * 8;
      *(short8*)&h0T[o] = z8;
      *(short8*)&h1T[o] = z8;
    }
  }
  __syncthreads();
  int maxlen = sLen[0];
  if (maxlen == 0) return;

  int w = tid >> 6;        // wave = col-tile rt (0..15)
  int rt = w;
  int l = tid & 63;
  int lrow = l & 15, lq = l >> 4;
  int c = rt * 16 + lrow;  // out-col 0..255

  const ushort_t* W1  = Wb;             // layer1
  const ushort_t* W0  = Wb + 393216;    // layer0
  const ushort_t* BSH = Wb + 786432;
  const ushort_t* BV1 = Wb + 802816;

  // per-lane bias preloads
  float bsh = b_shared[c];
  float br0 = b_ih[c] + b_hh[c];
  float bz0 = b_ih[256 + c] + b_hh[256 + c];
  float bi0 = b_ih[512 + c];
  float bh0 = b_hh[512 + c];
  float br1 = b_ih[768 + c] + b_hh[768 + c];
  float bz1 = b_ih[1024 + c] + b_hh[1024 + c];
  float bi1 = b_ih[1280 + c];
  float bh1 = b_hh[1280 + c];
  float bv1c = b_v1[c];
  float wv2c = w_v2[c];
  float bv2 = b_v2[0];

  int xr = tid >> 4;          // staging row 0..63
  int xg = tid & 15;          // 16 threads per row

  for (int p = 0; p < maxlen; ++p) {
    // ---- stage x(p) ----
    {
      int len = sLen[xr];
      int pc = p < (len - 1) ? p : (len > 0 ? len - 1 : 0);
      int t = sT0[xr] + pc;
      const float4 xv = *(const float4*)(x + ((size_t)t * B_ + sB[xr]) * 64 + xg * 4);
      ushort_t* d = &xT[aswz64(xr, xg * 4)];
      d[0] = f2bf(xv.x); d[1] = f2bf(xv.y); d[2] = f2bf(xv.z); d[3] = f2bf(xv.w);
    }
    __syncthreads();                                   // B1: xT ready

    // ---- feats GEMM ----
    {
      f32x4 fa[4];
#pragma unroll
      for (int mt = 0; mt < 4; ++mt) fa[mt] = {0.f, 0.f, 0.f, 0.f};
#pragma unroll
      for (int ks = 0; ks < 2; ++ks) {
        int kk = ks * 32 + lq * 8;
        short8 a[4];
#pragma unroll
        for (int mt = 0; mt < 4; ++mt)
          a[mt] = *(const short8*)&xT[aswz64(mt * 16 + lrow, kk)];
        short8 bf = *(const short8*)&BSH[(size_t)((rt * 2 + ks) << 9) + l * 8];
#pragma unroll
        for (int mt = 0; mt < 4; ++mt) fa[mt] = MFMA_BF16(a[mt], bf, fa[mt], 0, 0, 0);
      }
#pragma unroll
      for (int mt = 0; mt < 4; ++mt) {
#pragma unroll
        for (int rg = 0; rg < 4; ++rg) {
          int m = mt * 16 + lq * 4 + rg;
          float u = fa[mt][rg] + bsh;
          u = (u > 0.f) ? u : 0.01f * u;
          fT[aswz256(m, c)] = f2bf(u);
        }
      }
    }
    __syncthreads();                                   // B2: fT ready

    // ---- layer 0 ----
    {
      f32x4 accR[4], accZ[4], accI[4], accH[4];
#pragma unroll
      for (int mt = 0; mt < 4; ++mt) {
        accR[mt] = {0.f, 0.f, 0.f, 0.f}; accZ[mt] = {0.f, 0.f, 0.f, 0.f};
        accI[mt] = {0.f, 0.f, 0.f, 0.f}; accH[mt] = {0.f, 0.f, 0.f, 0.f};
      }
      gru_kloop(fT, h0T, W0, rt, lrow, lq, l, accR, accZ, accI, accH);
      __syncthreads();                                 // B3: all l0 reads done
      gru_epi(h0T, c, lq, br0, bz0, bi0, bh0, accR, accZ, accI, accH);
    }
    __syncthreads();                                   // B4: h0 new ready

    // ---- layer 1 ----
    {
      f32x4 accR[4], accZ[4], accI[4], accH[4];
#pragma unroll
      for (int mt = 0; mt < 4; ++mt) {
        accR[mt] = {0.f, 0.f, 0.f, 0.f}; accZ[mt] = {0.f, 0.f, 0.f, 0.f};
        accI[mt] = {0.f, 0.f, 0.f, 0.f}; accH[mt] = {0.f, 0.f, 0.f, 0.f};
      }
      gru_kloop(h0T, h1T, W1, rt, lrow, lq, l, accR, accZ, accI, accH);
      __syncthreads();                                 // B5: all l1 reads done
      gru_epi(h1T, c, lq, br1, bz1, bi1, bh1, accR, accZ, accI, accH);
    }
    __syncthreads();                                   // B6: h1 new ready

    // ---- value head ----
    {
      f32x4 av[4];
#pragma unroll
      for (int mt = 0; mt < 4; ++mt) av[mt] = {0.f, 0.f, 0.f, 0.f};
#pragma unroll
      for (int ks = 0; ks < 8; ++ks) {
        int kk = ks * 32 + lq * 8;
        short8 a[4];
#pragma unroll
        for (int mt = 0; mt < 4; ++mt)
          a[mt] = *(const short8*)&h1T[aswz256(mt * 16 + lrow, kk)];
        short8 bf = *(const short8*)&BV1[(size_t)((rt * 8 + ks) << 9) + l * 8];
#pragma unroll
        for (int mt = 0; mt < 4; ++mt) av[mt] = MFMA_BF16(a[mt], bf, av[mt], 0, 0, 0);
      }
#pragma unroll
      for (int mt = 0; mt < 4; ++mt) {
#pragma unroll
        for (int rg = 0; rg < 4; ++rg) {
          float u = av[mt][rg] + bv1c;
          u = (u > 0.f) ? u : 0.01f * u;
          float pv = u * wv2c;
          pv += __shfl_xor(pv, 1);
          pv += __shfl_xor(pv, 2);
          pv += __shfl_xor(pv, 4);
          pv += __shfl_xor(pv, 8);
          if (lrow == 0) vred[(mt * 16 + lq * 4 + rg) * 17 + rt] = pv;
        }
      }
    }
    __syncthreads();                                   // B7: vred ready

    // ---- outputs ----
    {
      int r = xr;
      bool vrow = (bid * 64 + r < nseg) && (p < sLen[r]);
      if (vrow) {
        int t = sT0[r] + p;
        if (xg == 0) {
          float s = 0.f;
#pragma unroll
          for (int ww = 0; ww < 16; ++ww) s += vred[r * 17 + ww];
          out[t * B_ + sB[r]] = s + bv2;
        }
        if (p == sLen[r] - 1 && t == T_ - 1) {
          int bb = sB[r];
#pragma unroll
          for (int q = 0; q < 16; ++q) {
            int cc = xg * 16 + q;
            out[131072 + bb * 256 + cc] = bf2f(h0T[aswz256(r, cc)]);
            out[131072 + 65536 + bb * 256 + cc] = bf2f(h1T[aswz256(r, cc)]);
          }
        }
      }
    }
    // no barrier needed: next stage writes xT only (nobody reads xT here)
  }
}

extern "C" void kernel_launch(void* const* d_in, const int* in_sizes, int n_in,
                              void* d_out, int out_size, void* d_ws, size_t ws_size,
                              hipStream_t stream) {
  const float* x        = (const float*)d_in[0];
  const int*   dones    = (const int*)d_in[1];
  const float* w_shared = (const float*)d_in[3];
  const float* b_shared = (const float*)d_in[4];
  const float* w_ih     = (const float*)d_in[5];
  const float* w_hh     = (const float*)d_in[6];
  const float* b_ih     = (const float*)d_in[7];
  const float* b_hh     = (const float*)d_in[8];
  const float* w_v1     = (const float*)d_in[9];
  const float* b_v1     = (const float*)d_in[10];
  const float* w_v2     = (const float*)d_in[11];
  const float* b_v2     = (const float*)d_in[12];
  float* out = (float*)d_out;

  ushort_t* Wb = (ushort_t*)d_ws;                         // 868352 ush
  uint_t* segs = (uint_t*)((char*)d_ws + 1736704);        // 131072 u32
  int* suf     = (int*)((char*)d_ws + 2260992);           // 514 i32
  int* gcur    = (int*)((char*)d_ws + 2263056);           // 513 i32

  hipFuncSetAttribute(reinterpret_cast<const void*>(k_rnn),
                      hipFuncAttributeMaxDynamicSharedMemorySize, 111616);

  hipMemsetAsync(gcur, 0, 513 * sizeof(int), stream);
  hipLaunchKernelGGL(k_prep, dim3(3392), dim3(256), 0, stream,
                     w_ih, w_hh, w_shared, w_v1, Wb);
  hipLaunchKernelGGL(k_hist, dim3(512), dim3(256), 0, stream, dones, gcur);
  hipLaunchKernelGGL(k_scan, dim3(1), dim3(64), 0, stream, gcur, suf);
  hipLaunchKernelGGL(k_place, dim3(512), dim3(256), 0, stream, dones, gcur, segs);
  hipLaunchKernelGGL(k_rnn, dim3(2048), dim3(1024), 111616, stream,
                     x, Wb, segs, suf, b_shared, b_ih, b_hh,
                     b_v1, w_v2, b_v2, out);
}

// Round 9
// 1131.373 us; speedup vs baseline: 2.0888x; 2.0888x over previous
//
#include <hip/hip_runtime.h>
#include <stdint.h>

#define T_ 512
#define B_ 256
#define H_ 256

typedef __attribute__((ext_vector_type(4))) float f32x4;
typedef __attribute__((ext_vector_type(8))) short short8;
typedef unsigned short ushort_t;
typedef unsigned int uint_t;

__device__ __forceinline__ ushort_t f2bf(float f) {
  uint_t x = __float_as_uint(f);
  x += 0x7fffu + ((x >> 16) & 1u);
  return (ushort_t)(x >> 16);
}
__device__ __forceinline__ float bf2f(ushort_t u) {
  return __uint_as_float(((uint_t)u) << 16);
}
__device__ __forceinline__ float sigmoidf_(float x) {
  return 1.0f / (1.0f + __expf(-x));
}
__device__ __forceinline__ float tanhf_(float x) {
  return 1.0f - 2.0f / (__expf(2.0f * x) + 1.0f);
}

// ============ weight prep: fragment-linear bf16 tiles (R5, proven) ==========
__global__ __launch_bounds__(256) void k_prep(
    const float* __restrict__ w_ih, const float* __restrict__ w_hh,
    const float* __restrict__ w_shared, const float* __restrict__ w_v1,
    ushort_t* __restrict__ wdst) {
  int idx = blockIdx.x * 256 + threadIdx.x;
  if (idx >= 868352) return;
  float v;
  if (idx < 786432) {
    int half = (idx < 393216) ? 1 : 0;
    int d = (idx < 393216) ? idx : idx - 393216;
    const float* wi = w_ih + (half ? 196608 : 0);
    const float* wh = w_hh + (half ? 196608 : 0);
    if (d < 262144) {
      int t = d >> 9, q = d & 511, l = q >> 3, j = q & 7;
      int n = (t >> 4) * 16 + (l & 15);
      int k = (t & 15) * 32 + (l >> 4) * 8 + j;
      v = (k < 256) ? wi[n * 256 + k] : wh[n * 256 + (k - 256)];
    } else if (d < 327680) {
      int dd = d - 262144;
      int t = dd >> 9, q = dd & 511, l = q >> 3, j = q & 7;
      int n = (t >> 3) * 16 + (l & 15);
      int k = (t & 7) * 32 + (l >> 4) * 8 + j;
      v = wi[(512 + n) * 256 + k];
    } else {
      int dd = d - 327680;
      int t = dd >> 9, q = dd & 511, l = q >> 3, j = q & 7;
      int n = (t >> 3) * 16 + (l & 15);
      int k = (t & 7) * 32 + (l >> 4) * 8 + j;
      v = wh[(512 + n) * 256 + k];
    }
  } else if (idx < 802816) {
    int dd = idx - 786432;
    int t = dd >> 9, q = dd & 511, l = q >> 3, j = q & 7;
    int n = (t >> 1) * 16 + (l & 15);
    int k = (t & 1) * 32 + (l >> 4) * 8 + j;
    v = w_shared[n * 64 + k];
  } else {
    int dd = idx - 802816;
    int t = dd >> 9, q = dd & 511, l = q >> 3, j = q & 7;
    int n = (t >> 3) * 16 + (l & 15);
    int k = (t & 7) * 32 + (l >> 4) * 8 + j;
    v = w_v1[n * 256 + k];
  }
  wdst[idx] = f2bf(v);
}

// ============ parallel segment build ========================================
__global__ __launch_bounds__(256) void k_hist(
    const int* __restrict__ dones, int* __restrict__ gcur) {
  __shared__ int lh[513];
  int tid = threadIdx.x;
  for (int i = tid; i < 513; i += 256) lh[i] = 0;
  __syncthreads();
  int t = blockIdx.x, b = tid;
  bool start = (t == 0) || (dones[t * B_ + b] != 0);
  if (start) {
    int tt = t + 1;
    while (tt < T_ && dones[tt * B_ + b] == 0) ++tt;
    atomicAdd(&lh[tt - t], 1);
  }
  __syncthreads();
  for (int i = tid; i < 513; i += 256)
    if (lh[i]) atomicAdd(&gcur[i], lh[i]);
}

// parallel suffix scan: suf[k] = #segs len >= k; gcur[len] = placement base
__global__ __launch_bounds__(512) void k_scanP(
    int* __restrict__ gcur, int* __restrict__ suf) {
  __shared__ int s[513];
  int tid = threadIdx.x;
  int i = tid + 1;  // 1..512
  if (tid < 512) s[i] = gcur[i];
  __syncthreads();
  for (int off = 1; off < 513; off <<= 1) {
    int v = 0;
    if (tid < 512 && i + off <= 512) v = s[i + off];
    __syncthreads();
    if (tid < 512) s[i] += v;
    __syncthreads();
  }
  if (tid < 512) {
    suf[i] = s[i];
    gcur[i] = (i < 512) ? s[i + 1] : 0;
  }
  if (tid == 0) { suf[0] = s[1]; suf[513] = 0; }
}

__global__ __launch_bounds__(256) void k_place(
    const int* __restrict__ dones, int* __restrict__ gcur,
    uint_t* __restrict__ segs) {
  __shared__ int lh[513];
  __shared__ int lbase[513];
  int tid = threadIdx.x;
  for (int i = tid; i < 513; i += 256) lh[i] = 0;
  __syncthreads();
  int t = blockIdx.x, b = tid;
  bool start = (t == 0) || (dones[t * B_ + b] != 0);
  int len = 0, lrank = 0;
  if (start) {
    int tt = t + 1;
    while (tt < T_ && dones[tt * B_ + b] == 0) ++tt;
    len = tt - t;
    lrank = atomicAdd(&lh[len], 1);
  }
  __syncthreads();
  for (int i = tid; i < 513; i += 256)
    if (lh[i]) lbase[i] = atomicAdd(&gcur[i], lh[i]);
  __syncthreads();
  if (start)
    segs[lbase[len] + lrank] = ((uint_t)b << 20) | ((uint_t)t << 10) | (uint_t)len;
}

// ============ feats = leaky_relu(x @ w_shared.T + b_shared) -> bf16 =========
__global__ __launch_bounds__(256) void k_feats(
    const float* __restrict__ x, const ushort_t* __restrict__ BSH,
    const float* __restrict__ b_shared, ushort_t* __restrict__ feats) {
  __shared__ __align__(16) ushort_t As[32 * 72];
  int tid = threadIdx.x;
  int row0 = blockIdx.x * 32;
  {
    int r = tid >> 3;
    int k = (tid & 7) << 3;
    const float* src = x + (size_t)(row0 + r) * 64 + k;
    float4 f0 = *(const float4*)(src);
    float4 f1 = *(const float4*)(src + 4);
    ushort_t* d = &As[r * 72 + k];
    d[0] = f2bf(f0.x); d[1] = f2bf(f0.y); d[2] = f2bf(f0.z); d[3] = f2bf(f0.w);
    d[4] = f2bf(f1.x); d[5] = f2bf(f1.y); d[6] = f2bf(f1.z); d[7] = f2bf(f1.w);
  }
  __syncthreads();
  int w = tid >> 6, l = tid & 63;
  int lrow = l & 15, lq = l >> 4;
  f32x4 acc[2][4];
#pragma unroll
  for (int mt = 0; mt < 2; ++mt)
#pragma unroll
    for (int nt = 0; nt < 4; ++nt) acc[mt][nt] = {0.f, 0.f, 0.f, 0.f};
#pragma unroll
  for (int ks = 0; ks < 2; ++ks) {
    int kof = ks * 32 + lq * 8;
    short8 a0 = *(const short8*)&As[lrow * 72 + kof];
    short8 a1 = *(const short8*)&As[(16 + lrow) * 72 + kof];
#pragma unroll
    for (int nt = 0; nt < 4; ++nt) {
      short8 bf = *(const short8*)&BSH[(size_t)(((w * 4 + nt) * 2 + ks) << 9) + l * 8];
      acc[0][nt] = __builtin_amdgcn_mfma_f32_16x16x32_bf16(a0, bf, acc[0][nt], 0, 0, 0);
      acc[1][nt] = __builtin_amdgcn_mfma_f32_16x16x32_bf16(a1, bf, acc[1][nt], 0, 0, 0);
    }
  }
#pragma unroll
  for (int nt = 0; nt < 4; ++nt) {
    int c = w * 64 + nt * 16 + lrow;
    float bias = b_shared[c];
#pragma unroll
    for (int mt = 0; mt < 2; ++mt) {
#pragma unroll
      for (int rg = 0; rg < 4; ++rg) {
        int m = mt * 16 + lq * 4 + rg;
        float u = acc[mt][nt][rg] + bias;
        u = (u > 0.f) ? u : 0.01f * u;
        feats[(size_t)(row0 + m) * 256 + c] = f2bf(u);
      }
    }
  }
}

// ============ wavefront GRU step (R5, proven) ===============================
__device__ __forceinline__ int aswz(int m, int k) {
  return m * 512 + ((((k >> 3) ^ (m & 7)) << 3) | (k & 7));
}

#define MFMA_BF16 __builtin_amdgcn_mfma_f32_16x16x32_bf16

template <bool FULLK>
__device__ __forceinline__ void step_mfma(
    const ushort_t* As, const ushort_t* __restrict__ W,
    int rt, int lrow, int lq, int l,
    f32x4 (&accR)[4], f32x4 (&accZ)[4], f32x4 (&accI)[4], f32x4 (&accH)[4]) {
  const ushort_t* Win = W + 262144;
  const ushort_t* Whn = W + 327680;
  constexpr int KS_END = FULLK ? 16 : 8;
#pragma unroll
  for (int ks = 0; ks < KS_END; ++ks) {
    short8 a[4];
#pragma unroll
    for (int mt = 0; mt < 4; ++mt)
      a[mt] = *(const short8*)&As[aswz(mt * 16 + lrow, ks * 32 + lq * 8)];
    short8 bR = *(const short8*)&W[(size_t)((rt * 16 + ks) << 9) + l * 8];
    short8 bZ = *(const short8*)&W[(size_t)(((16 + rt) * 16 + ks) << 9) + l * 8];
#pragma unroll
    for (int mt = 0; mt < 4; ++mt) accR[mt] = MFMA_BF16(a[mt], bR, accR[mt], 0, 0, 0);
#pragma unroll
    for (int mt = 0; mt < 4; ++mt) accZ[mt] = MFMA_BF16(a[mt], bZ, accZ[mt], 0, 0, 0);
    if (ks < 8) {
      short8 bI = *(const short8*)&Win[(size_t)((rt * 8 + ks) << 9) + l * 8];
#pragma unroll
      for (int mt = 0; mt < 4; ++mt) accI[mt] = MFMA_BF16(a[mt], bI, accI[mt], 0, 0, 0);
    } else {
      short8 bH = *(const short8*)&Whn[(size_t)((rt * 8 + (ks - 8)) << 9) + l * 8];
#pragma unroll
      for (int mt = 0; mt < 4; ++mt) accH[mt] = MFMA_BF16(a[mt], bH, accH[mt], 0, 0, 0);
    }
  }
}

__global__ __launch_bounds__(512, 4) void k_step(
    const ushort_t* __restrict__ feats, ushort_t* __restrict__ H0,
    ushort_t* __restrict__ H1, const ushort_t* __restrict__ Wb,
    const uint_t* __restrict__ segs, const int* __restrict__ suf,
    const float* __restrict__ b_ih, const float* __restrict__ b_hh,
    int iter, int nb0) {
  int bid = blockIdx.x;
  int onb = bid & 1;
  int rb = bid >> 1;
  int job = (rb >= nb0) ? 1 : 0;
  if (job && iter == 0) return;
  int count = job ? suf[iter] : suf[iter + 1];
  int brow = (job ? rb - nb0 : rb) * 64;
  if (brow >= count) return;
  int pos = job ? iter - 1 : iter;
  const ushort_t* srcLo = job ? H0 : feats;
  const ushort_t* srcHi = job ? H1 : H0;
  ushort_t* dst = job ? H1 : H0;
  const ushort_t* W = Wb + (job ? 0 : 393216);
  const float* bih = b_ih + job * 768;
  const float* bhh = b_hh + job * 768;

  __shared__ __align__(16) ushort_t As[64 * 512];

  int tid = threadIdx.x;
  short8 zero8 = {0, 0, 0, 0, 0, 0, 0, 0};
#pragma unroll
  for (int q = 0; q < 8; ++q) {
    int chunk = tid + 512 * q;
    int r = chunk >> 6;
    int kg = chunk & 63;
    int kc = kg << 3;
    int j = brow + r;
    if (j > count - 1) j = count - 1;
    uint_t sg = segs[j];
    int sb = sg >> 20;
    int st0 = (sg >> 10) & 1023;
    int t = st0 + pos;
    ushort_t* d = &As[r * 512 + ((kg ^ (r & 7)) << 3)];
    if (kc < 256) {
      *(short8*)d = *(const short8*)(srcLo + (size_t)(t * B_ + sb) * 256 + kc);
    } else if (pos == 0) {
      *(short8*)d = zero8;
    } else {
      *(short8*)d = *(const short8*)(srcHi + (size_t)((t - 1) * B_ + sb) * 256 + (kc - 256));
    }
  }
  __syncthreads();

  int nw = tid >> 6;
  int l = tid & 63;
  int lrow = l & 15, lq = l >> 4;
  int rt = onb * 8 + nw;

  f32x4 accR[4], accZ[4], accI[4], accH[4];
#pragma unroll
  for (int mt = 0; mt < 4; ++mt) {
    accR[mt] = {0.f, 0.f, 0.f, 0.f};
    accZ[mt] = {0.f, 0.f, 0.f, 0.f};
    accI[mt] = {0.f, 0.f, 0.f, 0.f};
    accH[mt] = {0.f, 0.f, 0.f, 0.f};
  }
  if (pos == 0) step_mfma<false>(As, W, rt, lrow, lq, l, accR, accZ, accI, accH);
  else          step_mfma<true >(As, W, rt, lrow, lq, l, accR, accZ, accI, accH);

  int c = rt * 16 + lrow;
  float br = bih[c] + bhh[c];
  float bz = bih[256 + c] + bhh[256 + c];
  float bi = bih[512 + c];
  float bh = bhh[512 + c];
#pragma unroll
  for (int mt = 0; mt < 4; ++mt) {
#pragma unroll
    for (int rg = 0; rg < 4; ++rg) {
      int m = mt * 16 + lq * 4 + rg;
      bool valid = (brow + m) < count;
      uint_t sg = segs[valid ? (brow + m) : (count - 1)];
      int rowIdx = (((int)((sg >> 10) & 1023) + pos)) * B_ + (int)(sg >> 20);
      float rr = sigmoidf_(accR[mt][rg] + br);
      float zz = sigmoidf_(accZ[mt][rg] + bz);
      float nn = tanhf_(accI[mt][rg] + bi + rr * (accH[mt][rg] + bh));
      float hp = bf2f(As[aswz(m, 256 + c)]);
      float h = (1.f - zz) * nn + zz * hp;
      if (valid) dst[(size_t)rowIdx * 256 + c] = f2bf(h);
    }
  }
}

// ============ persistent tail: positions >= 8 (R7-proven inner loop) ========
__device__ __forceinline__ int aswz256(int m, int k) {
  return m * 256 + ((((k >> 3) ^ (m & 7)) << 3) | (k & 7));
}

__device__ __forceinline__ void gru_kloop(
    const ushort_t* __restrict__ Alo, const ushort_t* __restrict__ hT,
    const ushort_t* __restrict__ Wl, int rt, int lrow, int lq, int l,
    f32x4 (&accR)[4], f32x4 (&accZ)[4], f32x4 (&accI)[4], f32x4 (&accH)[4]) {
  const ushort_t* Win = Wl + 262144;
  const ushort_t* Whn = Wl + 327680;
#pragma unroll
  for (int ks = 0; ks < 16; ++ks) {
    const ushort_t* atile = (ks < 8) ? Alo : hT;
    int kk = (ks & 7) * 32 + lq * 8;
    short8 a[4];
#pragma unroll
    for (int mt = 0; mt < 4; ++mt)
      a[mt] = *(const short8*)&atile[aswz256(mt * 16 + lrow, kk)];
    short8 bR = *(const short8*)&Wl[(size_t)((rt * 16 + ks) << 9) + l * 8];
    short8 bZ = *(const short8*)&Wl[(size_t)(((16 + rt) * 16 + ks) << 9) + l * 8];
#pragma unroll
    for (int mt = 0; mt < 4; ++mt) accR[mt] = MFMA_BF16(a[mt], bR, accR[mt], 0, 0, 0);
#pragma unroll
    for (int mt = 0; mt < 4; ++mt) accZ[mt] = MFMA_BF16(a[mt], bZ, accZ[mt], 0, 0, 0);
    if (ks < 8) {
      short8 bI = *(const short8*)&Win[(size_t)((rt * 8 + ks) << 9) + l * 8];
#pragma unroll
      for (int mt = 0; mt < 4; ++mt) accI[mt] = MFMA_BF16(a[mt], bI, accI[mt], 0, 0, 0);
    } else {
      short8 bH = *(const short8*)&Whn[(size_t)((rt * 8 + (ks - 8)) << 9) + l * 8];
#pragma unroll
      for (int mt = 0; mt < 4; ++mt) accH[mt] = MFMA_BF16(a[mt], bH, accH[mt], 0, 0, 0);
    }
  }
}

__device__ __forceinline__ void tail_epi_write(
    ushort_t* hT, ushort_t* __restrict__ Hg,
    const int* sB, const int* sT0, const int* sLen,
    int q, int c, int lq,
    float br, float bz, float bi, float bh,
    f32x4 (&accR)[4], f32x4 (&accZ)[4], f32x4 (&accI)[4], f32x4 (&accH)[4]) {
#pragma unroll
  for (int mt = 0; mt < 4; ++mt) {
#pragma unroll
    for (int rg = 0; rg < 4; ++rg) {
      int m = mt * 16 + lq * 4 + rg;
      float hp = bf2f(hT[aswz256(m, c)]);
      float rr = sigmoidf_(accR[mt][rg] + br);
      float zz = sigmoidf_(accZ[mt][rg] + bz);
      float nn = tanhf_(accI[mt][rg] + bi + rr * (accH[mt][rg] + bh));
      float h = (1.f - zz) * nn + zz * hp;
      if (q < sLen[m]) {
        ushort_t hb = f2bf(h);
        hT[aswz256(m, c)] = hb;
        Hg[((size_t)(sT0[m] + q) * B_ + sB[m]) * 256 + c] = hb;
      }
    }
  }
}

__global__ __launch_bounds__(1024, 4) void k_tail(
    const ushort_t* __restrict__ feats, ushort_t* __restrict__ H0,
    ushort_t* __restrict__ H1, const ushort_t* __restrict__ Wb,
    const uint_t* __restrict__ segs, const int* __restrict__ suf,
    const float* __restrict__ b_ih, const float* __restrict__ b_hh) {
  extern __shared__ __align__(16) ushort_t dyn[];
  ushort_t* fT  = dyn;            // 64x256
  ushort_t* h0T = dyn + 16384;
  ushort_t* h1T = dyn + 32768;
  int* sB   = (int*)((char*)dyn + 98304);
  int* sT0  = sB + 64;
  int* sLen = sB + 128;           // 99072 B

  int tid = threadIdx.x, bid = blockIdx.x;
  int count = suf[8];
  int brow = bid * 64;
  if (brow >= count) return;

  if (tid < 64) {
    int j = brow + tid;
    int jc = (j < count) ? j : (count - 1);
    uint_t sg = segs[jc];
    sB[tid] = (int)(sg >> 20);
    sT0[tid] = (int)((sg >> 10) & 1023);
    sLen[tid] = (j < count) ? (int)(sg & 1023) : 0;
  }
  __syncthreads();
  int maxp = sLen[0];

  // load h0 @ pos 7, h1 @ pos 6 (all rows have len >= 8)
#pragma unroll
  for (int q = 0; q < 4; ++q) {
    int chunk = tid + 1024 * q;
    int arr = chunk >> 11;
    int cc = chunk & 2047;
    int r = cc >> 5, kg = cc & 31, kc = kg << 3;
    int len = sLen[r];
    int pc = arr ? 6 : 7;
    if (pc > len - 1) pc = (len > 0) ? (len - 1) : 0;
    const ushort_t* src = arr ? H1 : H0;
    ushort_t* dstT = arr ? h1T : h0T;
    *(short8*)&dstT[r * 256 + ((kg ^ (r & 7)) << 3)] =
        *(const short8*)&src[((size_t)(sT0[r] + pc) * B_ + sB[r]) * 256 + kc];
  }
  __syncthreads();

  int w = tid >> 6;
  int rt = w;
  int l = tid & 63;
  int lrow = l & 15, lq = l >> 4;
  int c = rt * 16 + lrow;

  const ushort_t* W1 = Wb;
  const ushort_t* W0 = Wb + 393216;
  float br0 = b_ih[c] + b_hh[c];
  float bz0 = b_ih[256 + c] + b_hh[256 + c];
  float bi0 = b_ih[512 + c];
  float bh0 = b_hh[512 + c];
  float br1 = b_ih[768 + c] + b_hh[768 + c];
  float bz1 = b_ih[1024 + c] + b_hh[1024 + c];
  float bi1 = b_ih[1280 + c];
  float bh1 = b_hh[1280 + c];

  for (int p = 8; p <= maxp; ++p) {
    // layer1 @ pos p-1
    {
      f32x4 aR[4], aZ[4], aI[4], aH[4];
#pragma unroll
      for (int mt = 0; mt < 4; ++mt) {
        aR[mt] = {0.f, 0.f, 0.f, 0.f}; aZ[mt] = {0.f, 0.f, 0.f, 0.f};
        aI[mt] = {0.f, 0.f, 0.f, 0.f}; aH[mt] = {0.f, 0.f, 0.f, 0.f};
      }
      gru_kloop(h0T, h1T, W1, rt, lrow, lq, l, aR, aZ, aI, aH);
      __syncthreads();
      tail_epi_write(h1T, H1, sB, sT0, sLen, p - 1, c, lq,
                     br1, bz1, bi1, bh1, aR, aZ, aI, aH);
    }
    __syncthreads();
    if (p == maxp) break;

    // stage feats @ pos p
#pragma unroll
    for (int q = 0; q < 2; ++q) {
      int chunk = tid + 1024 * q;
      int r = chunk >> 5, kg = chunk & 31, kc = kg << 3;
      int len = sLen[r];
      int pc = p;
      if (pc > len - 1) pc = (len > 0) ? (len - 1) : 0;
      *(short8*)&fT[r * 256 + ((kg ^ (r & 7)) << 3)] =
          *(const short8*)&feats[((size_t)(sT0[r] + pc) * B_ + sB[r]) * 256 + kc];
    }
    __syncthreads();

    // layer0 @ pos p
    {
      f32x4 aR[4], aZ[4], aI[4], aH[4];
#pragma unroll
      for (int mt = 0; mt < 4; ++mt) {
        aR[mt] = {0.f, 0.f, 0.f, 0.f}; aZ[mt] = {0.f, 0.f, 0.f, 0.f};
        aI[mt] = {0.f, 0.f, 0.f, 0.f}; aH[mt] = {0.f, 0.f, 0.f, 0.f};
      }
      gru_kloop(fT, h0T, W0, rt, lrow, lq, l, aR, aZ, aI, aH);
      __syncthreads();
      tail_epi_write(h0T, H0, sB, sT0, sLen, p, c, lq,
                     br0, bz0, bi0, bh0, aR, aZ, aI, aH);
    }
    __syncthreads();
  }
}

// ============ value head + merged h_final ===================================
__global__ __launch_bounds__(256) void k_value(
    const ushort_t* __restrict__ H1, const ushort_t* __restrict__ BV1,
    const float* __restrict__ b_v1, const float* __restrict__ w_v2,
    const float* __restrict__ b_v2, float* __restrict__ vout,
    const ushort_t* __restrict__ H0) {
  __shared__ __align__(16) ushort_t As[32 * 264];
  __shared__ float vred[32 * 65];
  int tid = threadIdx.x;
  int row0 = blockIdx.x * 32;
#pragma unroll
  for (int q = 0; q < 4; ++q) {
    int chunk = tid + 256 * q;
    int r = chunk >> 5;
    int kc = (chunk & 31) << 3;
    *(short8*)&As[r * 264 + kc] = *(const short8*)&H1[(size_t)(row0 + r) * 256 + kc];
  }
  __syncthreads();
  int w = tid >> 6, l = tid & 63;
  int lrow = l & 15, lq = l >> 4;
  f32x4 acc[2][4];
#pragma unroll
  for (int mt = 0; mt < 2; ++mt)
#pragma unroll
    for (int nt = 0; nt < 4; ++nt) acc[mt][nt] = {0.f, 0.f, 0.f, 0.f};
#pragma unroll
  for (int ks = 0; ks < 8; ++ks) {
    int kof = ks * 32 + lq * 8;
    short8 a0 = *(const short8*)&As[lrow * 264 + kof];
    short8 a1 = *(const short8*)&As[(16 + lrow) * 264 + kof];
#pragma unroll
    for (int nt = 0; nt < 4; ++nt) {
      short8 bf = *(const short8*)&BV1[(size_t)(((w * 4 + nt) * 8 + ks) << 9) + l * 8];
      acc[0][nt] = MFMA_BF16(a0, bf, acc[0][nt], 0, 0, 0);
      acc[1][nt] = MFMA_BF16(a1, bf, acc[1][nt], 0, 0, 0);
    }
  }
#pragma unroll
  for (int mt = 0; mt < 2; ++mt) {
#pragma unroll
    for (int rg = 0; rg < 4; ++rg) {
      float p = 0.f;
#pragma unroll
      for (int nt = 0; nt < 4; ++nt) {
        int c = w * 64 + nt * 16 + lrow;
        float u = acc[mt][nt][rg] + b_v1[c];
        u = (u > 0.f) ? u : 0.01f * u;
        p += u * w_v2[c];
      }
      int m = mt * 16 + lq * 4 + rg;
      vred[m * 65 + w * 16 + lrow] = p;
    }
  }
  __syncthreads();
  if (tid < 32) {
    float s = 0.f;
#pragma unroll
    for (int j = 0; j < 64; ++j) s += vred[tid * 65 + j];
    vout[row0 + tid] = s + b_v2[0];
  }
  if (blockIdx.x < 512) {
    int idx = blockIdx.x * 256 + tid;
    int lyr = idx >> 16;
    int rem = idx & 65535;
    const ushort_t* src = lyr ? H1 : H0;
    vout[131072 + idx] = bf2f(src[(size_t)511 * 65536 + rem]);
  }
}

extern "C" void kernel_launch(void* const* d_in, const int* in_sizes, int n_in,
                              void* d_out, int out_size, void* d_ws, size_t ws_size,
                              hipStream_t stream) {
  const float* x        = (const float*)d_in[0];
  const int*   dones    = (const int*)d_in[1];
  const float* w_shared = (const float*)d_in[3];
  const float* b_shared = (const float*)d_in[4];
  const float* w_ih     = (const float*)d_in[5];
  const float* w_hh     = (const float*)d_in[6];
  const float* b_ih     = (const float*)d_in[7];
  const float* b_hh     = (const float*)d_in[8];
  const float* w_v1     = (const float*)d_in[9];
  const float* b_v1     = (const float*)d_in[10];
  const float* w_v2     = (const float*)d_in[11];
  const float* b_v2     = (const float*)d_in[12];
  float* out = (float*)d_out;

  ushort_t* ws16 = (ushort_t*)d_ws;
  ushort_t* feats = ws16;                       // 33554432 elems
  ushort_t* H0    = ws16 + 33554432;
  ushort_t* H1    = ws16 + 67108864;
  ushort_t* Wb    = ws16 + 100663296;           // 868352 elems
  ushort_t* BSH   = Wb + 786432;
  ushort_t* BV1   = Wb + 802816;
  uint_t* segs = (uint_t*)((char*)d_ws + 203063296);  // 131072 u32
  int* suf     = (int*)((char*)d_ws + 203587584);     // 514 i32
  int* gcur    = (int*)((char*)d_ws + 203589648);     // 513 i32

  hipFuncSetAttribute(reinterpret_cast<const void*>(k_tail),
                      hipFuncAttributeMaxDynamicSharedMemorySize, 99072);

  hipMemsetAsync(gcur, 0, 513 * sizeof(int), stream);
  hipLaunchKernelGGL(k_prep, dim3(3392), dim3(256), 0, stream,
                     w_ih, w_hh, w_shared, w_v1, Wb);
  hipLaunchKernelGGL(k_hist, dim3(512), dim3(256), 0, stream, dones, gcur);
  hipLaunchKernelGGL(k_scanP, dim3(1), dim3(512), 0, stream, gcur, suf);
  hipLaunchKernelGGL(k_place, dim3(512), dim3(256), 0, stream, dones, gcur, segs);
  hipLaunchKernelGGL(k_feats, dim3(4096), dim3(256), 0, stream,
                     x, BSH, b_shared, feats);
  for (int i = 0; i < 8; ++i) {
    int nb0 = (131072 / (i + 1) + 63) / 64;
    int nb1 = (i == 0) ? 0 : ((131072 / i + 63) / 64);
    hipLaunchKernelGGL(k_step, dim3((nb0 + nb1) * 2), dim3(512), 0, stream,
                       feats, H0, H1, Wb, segs, suf, b_ih, b_hh, i, nb0);
  }
  hipLaunchKernelGGL(k_tail, dim3(256), dim3(1024), 99072, stream,
                     feats, H0, H1, Wb, segs, suf, b_ih, b_hh);
  hipLaunchKernelGGL(k_value, dim3(4096), dim3(256), 0, stream,
                     H1, BV1, b_v1, w_v2, b_v2, out, H0);
}